// Round 12
// baseline (289.072 us; speedup 1.0000x reference)
//
#include <hip/hip_runtime.h>
#include <hip/hip_fp16.h>

#define N_NODES 50000
#define N_EDGES 1250000
#define HID 64
#define N_LAYERS 3
#define N_GRAPHS 64
#define EPS 1e-5f

// ---- dst-partitioned CSR build ----
#define P_SHIFT 7
#define P_NODES 128                                     // nodes per partition
#define NP ((N_NODES + P_NODES - 1) / P_NODES)          // 391
#define PCAP 4096                                       // slots (mean 3200, +16 sigma)

#define LB_NODES 8                                      // nodes per k_layer block

__device__ inline float2 up2(unsigned u) {
    __half2 h;
    *reinterpret_cast<unsigned*>(&h) = u;
    return __half22float2(h);
}
__device__ inline unsigned pk2(float a, float b) {
    __half2 h = __floats2half2_rn(a, b);
    return *reinterpret_cast<unsigned*>(&h);
}

// ------- embed gather: h0[i][:] = fp16(emb[x[i]][:]) ------------------------
__global__ __launch_bounds__(256) void k_embed(const int* __restrict__ x,
                                               const float4* __restrict__ emb4,
                                               uint4* __restrict__ h8) {
    int i = blockIdx.x * 256 + threadIdx.x;           // over N_NODES * 8
    if (i < N_NODES * 8) {
        int row = i >> 3, q = i & 7;
        float4 fa = emb4[x[row] * 16 + q * 2];
        float4 fb = emb4[x[row] * 16 + q * 2 + 1];
        uint4 u;
        u.x = pk2(fa.x, fa.y); u.y = pk2(fa.z, fa.w);
        u.z = pk2(fb.x, fb.y); u.w = pk2(fb.z, fb.w);
        h8[i] = u;
    }
}

// ---- partition edges by dst>>7; per-block contiguous runs (low write-amp) --
__global__ __launch_bounds__(1024) void k_part(const int* __restrict__ src,
                                               const int* __restrict__ dst,
                                               const float* __restrict__ w,
                                               int* __restrict__ pcnt,
                                               int2* __restrict__ part) {
    __shared__ int hist[NP];   // counts, then block base
    __shared__ int cur[NP];
    int t = threadIdx.x;
    for (int k = t; k < NP; k += 1024) { hist[k] = 0; cur[k] = 0; }
    __syncthreads();
    int chunk = (N_EDGES + gridDim.x - 1) / gridDim.x;
    int e0 = blockIdx.x * chunk;
    int e1 = min(e0 + chunk, N_EDGES);
    for (int e = e0 + t; e < e1; e += 1024)
        atomicAdd(&hist[dst[e] >> P_SHIFT], 1);
    __syncthreads();
    for (int k = t; k < NP; k += 1024) {
        int c = hist[k];
        hist[k] = c ? atomicAdd(&pcnt[k], c) : 0;      // reserve block range
    }
    __syncthreads();
    for (int e = e0 + t; e < e1; e += 1024) {
        int d = dst[e];
        int b = d >> P_SHIFT;
        int r = atomicAdd(&cur[b], 1);
        part[(b << 12) + hist[b] + r] =                // PCAP == 4096
            make_int2(((d & (P_NODES - 1)) << 16) | src[e], __float_as_int(w[e]));
    }
}

// ---- per-partition LDS counting sort -> packed 4B CSR ----------------------
// entry = src:16 | half(w):16 ; per-node-contiguous; dst implicit via rowbeg.
// block 0 also computes graph bounds + zeroes pooling scratch
__global__ __launch_bounds__(512) void k_sort(const int2* __restrict__ part,
                                              const int* __restrict__ pcnt,
                                              unsigned* __restrict__ csr16,
                                              int* __restrict__ rowbeg,
                                              int* __restrict__ rowend,
                                              const int* __restrict__ batch,
                                              int* __restrict__ start,
                                              float* __restrict__ sums,
                                              unsigned* __restrict__ maxs) {
    __shared__ int2 sbuf[PCAP];        // 32 KB
    __shared__ int cnt[P_NODES], base[P_NODES], cur[P_NODES];
    int p = blockIdx.x, t = threadIdx.x;
    if (t < P_NODES) cnt[t] = 0;
    __syncthreads();
    int n = pcnt[p];
    if (n > PCAP) n = PCAP;
    const int2* pb = part + (p << 12);
    for (int i = t; i < n; i += 512) atomicAdd(&cnt[pb[i].x >> 16], 1);
    __syncthreads();
    if (t < P_NODES) base[t] = cnt[t];
    __syncthreads();
    for (int off = 1; off < P_NODES; off <<= 1) {
        int v = (t < P_NODES && t >= off) ? base[t - off] : 0;
        __syncthreads();
        if (t < P_NODES) base[t] += v;                 // inclusive scan
        __syncthreads();
    }
    if (t < P_NODES) cur[t] = base[t] - cnt[t];        // exclusive start
    __syncthreads();
    for (int i = t; i < n; i += 512) {
        int2 e = pb[i];
        int pos = atomicAdd(&cur[e.x >> 16], 1);
        sbuf[pos] = e;
    }
    __syncthreads();
    for (int i = t; i < n; i += 512) {                 // packed 4B write
        int2 e = sbuf[i];
        unsigned short wb = __half_as_ushort(__float2half_rn(__int_as_float(e.y)));
        csr16[(p << 12) + i] = (unsigned)(e.x & 0xFFFF) | ((unsigned)wb << 16);
    }
    if (t < P_NODES) {
        int node = p * P_NODES + t;
        if (node < N_NODES) {
            rowbeg[node] = (p << 12) + base[t] - cnt[t];
            rowend[node] = (p << 12) + base[t];
        }
    }
    if (p == 0) {                                      // fused misc work
        if (t <= N_GRAPHS) {
            int lo = 0, hi = N_NODES;
            while (lo < hi) {
                int mid = (lo + hi) >> 1;
                if (batch[mid] < t) lo = mid + 1; else hi = mid;
            }
            start[t] = lo;
        }
        for (int k = t; k < N_GRAPHS * HID; k += 512) {
            sums[k] = 0.f;
            maxs[k] = 0u;
        }
    }
}

// ---- fused layer: fp16 8-lane-row gather -> agg -> @W -> bias+LN+ReLU ------
// 512 thr = 8 waves; wave = one node. Gather: lane = (grp = lane>>3 edge-slot
// owner, c8 = lane&7 channel-octet); dwordx4 = 8 fp16 channels; 8 rows per
// instruction across the wave; 4 edge-slots (32 edges) in flight per iter.
__global__ __launch_bounds__(512) void k_layer(const uint4* __restrict__ h8,
                                               const int* __restrict__ rowbeg,
                                               const int* __restrict__ rowend,
                                               const unsigned* __restrict__ csr16,
                                               const float* __restrict__ W,
                                               const float* __restrict__ bias,
                                               const float* __restrict__ g,
                                               const float* __restrict__ b,
                                               unsigned short* __restrict__ hout) {
    __shared__ float Wl[HID * HID];           // 16 KB
    __shared__ float aggl[LB_NODES][HID];     // 2 KB
    int tid = threadIdx.x;
    for (int k = tid; k < HID * HID; k += 512) Wl[k] = W[k];
    __syncthreads();
    int wv = tid >> 6, lane = tid & 63;
    int grp = lane >> 3, c8 = lane & 7;
    int row = blockIdx.x * LB_NODES + wv;     // 50000 % 8 == 0 -> exact
    int p0 = __builtin_amdgcn_readfirstlane(rowbeg[row]);
    int p1 = __builtin_amdgcn_readfirstlane(rowend[row]);
    int last = p1 - 1;
    float A0[8], A1[8], A2[8], A3[8];
#pragma unroll
    for (int q = 0; q < 8; ++q) { A0[q] = 0.f; A1[q] = 0.f; A2[q] = 0.f; A3[q] = 0.f; }
    for (int p = p0; p <= last; p += 32) {    // 32 edges per iter, 4 slots
        int i0 = p + grp, i1 = i0 + 8, i2 = i0 + 16, i3 = i0 + 24;
        unsigned e0 = csr16[min(i0, last)];
        unsigned e1 = csr16[min(i1, last)];
        unsigned e2 = csr16[min(i2, last)];
        unsigned e3 = csr16[min(i3, last)];
        float w0 = (i0 <= last) ? __half2float(__ushort_as_half((unsigned short)(e0 >> 16))) : 0.f;
        float w1 = (i1 <= last) ? __half2float(__ushort_as_half((unsigned short)(e1 >> 16))) : 0.f;
        float w2 = (i2 <= last) ? __half2float(__ushort_as_half((unsigned short)(e2 >> 16))) : 0.f;
        float w3 = (i3 <= last) ? __half2float(__ushort_as_half((unsigned short)(e3 >> 16))) : 0.f;
        uint4 v0 = h8[(e0 & 0xFFFF) * 8 + c8];
        uint4 v1 = h8[(e1 & 0xFFFF) * 8 + c8];
        uint4 v2 = h8[(e2 & 0xFFFF) * 8 + c8];
        uint4 v3 = h8[(e3 & 0xFFFF) * 8 + c8];
        float2 f;
        f = up2(v0.x); A0[0] += f.x * w0; A0[1] += f.y * w0;
        f = up2(v0.y); A0[2] += f.x * w0; A0[3] += f.y * w0;
        f = up2(v0.z); A0[4] += f.x * w0; A0[5] += f.y * w0;
        f = up2(v0.w); A0[6] += f.x * w0; A0[7] += f.y * w0;
        f = up2(v1.x); A1[0] += f.x * w1; A1[1] += f.y * w1;
        f = up2(v1.y); A1[2] += f.x * w1; A1[3] += f.y * w1;
        f = up2(v1.z); A1[4] += f.x * w1; A1[5] += f.y * w1;
        f = up2(v1.w); A1[6] += f.x * w1; A1[7] += f.y * w1;
        f = up2(v2.x); A2[0] += f.x * w2; A2[1] += f.y * w2;
        f = up2(v2.y); A2[2] += f.x * w2; A2[3] += f.y * w2;
        f = up2(v2.z); A2[4] += f.x * w2; A2[5] += f.y * w2;
        f = up2(v2.w); A2[6] += f.x * w2; A2[7] += f.y * w2;
        f = up2(v3.x); A3[0] += f.x * w3; A3[1] += f.y * w3;
        f = up2(v3.y); A3[2] += f.x * w3; A3[3] += f.y * w3;
        f = up2(v3.z); A3[4] += f.x * w3; A3[5] += f.y * w3;
        f = up2(v3.w); A3[6] += f.x * w3; A3[7] += f.y * w3;
    }
    float acc[8];
#pragma unroll
    for (int q = 0; q < 8; ++q) {
        float s = (A0[q] + A1[q]) + (A2[q] + A3[q]);
        s += __shfl_xor(s, 8, 64);
        s += __shfl_xor(s, 16, 64);
        s += __shfl_xor(s, 32, 64);
        acc[q] = s;
    }
    if (grp == 0) {
#pragma unroll
        for (int q = 0; q < 8; ++q) aggl[wv][c8 * 8 + q] = acc[q];
    }
    // ---- dense transform (per-wave matvec, 1 channel/lane) ----
    const float* agg = &aggl[wv][0];
    int j = lane;
    float mv = 0.f;
#pragma unroll 16
    for (int k = 0; k < HID; ++k) mv += agg[k] * Wl[k * HID + j];
    float v = mv + bias[j];
    float s = v;
#pragma unroll
    for (int off = 32; off; off >>= 1) s += __shfl_xor(s, off, 64);
    float mu = s * (1.f / 64.f);
    float d = v - mu;
    float vv = d * d;
#pragma unroll
    for (int off = 32; off; off >>= 1) vv += __shfl_xor(vv, off, 64);
    float var = vv * (1.f / 64.f);
    float y = fmaxf(d * rsqrtf(var + EPS) * g[j] + b[j], 0.f);
    hout[row * HID + j] = __half_as_ushort(__float2half_rn(y));
}

// ---------------- pooling: sliced segmented reduction (fp16 input) ----------
#define NSLICE 16
__global__ __launch_bounds__(256) void k_pool2(const unsigned short* __restrict__ h,
                                               const int* __restrict__ start,
                                               float* __restrict__ sums,
                                               unsigned* __restrict__ maxs) {
    int gph = blockIdx.x >> 4;          // / NSLICE
    int sl  = blockIdx.x & (NSLICE - 1);
    int s = start[gph], e1 = start[gph + 1];
    int len = e1 - s;
    int chunk = (len + NSLICE - 1) / NSLICE;
    int r0 = s + sl * chunk;
    int r1 = min(r0 + chunk, e1);
    int j = threadIdx.x & 63, wv = threadIdx.x >> 6;
    float sm = 0.f, mx = 0.f;           // post-ReLU values >= 0
    for (int r = r0 + wv; r < r1; r += 4) {
        float v = __half2float(__ushort_as_half(h[r * HID + j]));
        sm += v;
        mx = fmaxf(mx, v);
    }
    atomicAdd(&sums[gph * HID + j], sm);
    atomicMax(&maxs[gph * HID + j], __float_as_uint(mx));
}

// ---------------- final MLP: relu([mean,max] @ W1 + b1) @ W2 + b2 -----------
__global__ __launch_bounds__(64) void k_mlp(const float* __restrict__ sums,
                                            const unsigned* __restrict__ maxs,
                                            const int* __restrict__ start,
                                            const float* __restrict__ W1,
                                            const float* __restrict__ b1,
                                            const float* __restrict__ W2,
                                            const float* __restrict__ b2,
                                            float* __restrict__ out) {
    int gph = blockIdx.x;
    int j = threadIdx.x;          // 64 threads
    __shared__ float gv[2 * HID];
    int cnt = start[gph + 1] - start[gph];
    float inv = 1.f / fmaxf((float)cnt, 1.f);
    gv[j] = sums[gph * HID + j] * inv;
    float mx = __uint_as_float(maxs[gph * HID + j]);
    gv[HID + j] = (cnt > 0) ? mx : 0.f;
    __syncthreads();
    float acc = b1[j];
#pragma unroll
    for (int k = 0; k < 2 * HID; ++k) acc += gv[k] * W1[k * HID + j];
    acc = fmaxf(acc, 0.f);
    float p = acc * W2[j];
#pragma unroll
    for (int off = 32; off; off >>= 1) p += __shfl_xor(p, off, 64);
    if (j == 0) out[gph] = p + b2[0];
}

extern "C" void kernel_launch(void* const* d_in, const int* in_sizes, int n_in,
                              void* d_out, int out_size, void* d_ws, size_t ws_size,
                              hipStream_t stream) {
    const int*   x     = (const int*)d_in[0];
    const int*   ei    = (const int*)d_in[1];
    const float* ew    = (const float*)d_in[2];
    const int*   batch = (const int*)d_in[3];
    const float* emb   = (const float*)d_in[4];
    const float* convW = (const float*)d_in[5];
    const float* convB = (const float*)d_in[6];
    const float* lnG   = (const float*)d_in[7];
    const float* lnB   = (const float*)d_in[8];
    const float* W1    = (const float*)d_in[9];
    const float* b1    = (const float*)d_in[10];
    const float* W2    = (const float*)d_in[11];
    const float* b2    = (const float*)d_in[12];
    float* out = (float*)d_out;

    // ---- workspace layout (~32 MB) ----
    unsigned short* hA = (unsigned short*)d_ws;           // 6.4 MB (fp16)
    unsigned short* hB = hA + (size_t)N_NODES * HID;      // 6.4 MB (fp16)
    int2*  part   = (int2*)(hB + (size_t)N_NODES * HID);  // 12.81 MB
    unsigned* csr16 = (unsigned*)(part + (size_t)NP * PCAP); // 6.25 MB
    int*   pcnt   = (int*)(csr16 + (size_t)NP * PCAP);    // 391
    int*   rowbeg = pcnt + NP;                            // 50000
    int*   rowend = rowbeg + N_NODES;                     // 50000
    float* sums   = (float*)(rowend + N_NODES);           // 4096
    unsigned* maxs = (unsigned*)(sums + N_GRAPHS * HID);  // 4096
    int*   start  = (int*)(maxs + N_GRAPHS * HID);        // 65

    const int* src = ei;
    const int* dst = ei + N_EDGES;

    hipMemsetAsync(pcnt, 0, NP * sizeof(int), stream);
    k_part<<<256, 1024, 0, stream>>>(src, dst, ew, pcnt, part);
    k_sort<<<NP, 512, 0, stream>>>(part, pcnt, csr16, rowbeg, rowend,
                                   batch, start, sums, maxs);
    k_embed<<<(N_NODES * 8 + 255) / 256, 256, 0, stream>>>(
        x, (const float4*)emb, (uint4*)hA);

    unsigned short* bufs[2] = { hA, hB };
    for (int L = 0; L < N_LAYERS; ++L) {
        k_layer<<<N_NODES / LB_NODES, 512, 0, stream>>>(
            (const uint4*)bufs[L & 1], rowbeg, rowend, csr16,
            convW + L * HID * HID, convB + L * HID,
            lnG + L * HID, lnB + L * HID, bufs[(L + 1) & 1]);
    }
    const unsigned short* hfin = bufs[N_LAYERS & 1];      // hB after 3 layers

    k_pool2<<<N_GRAPHS * NSLICE, 256, 0, stream>>>(hfin, start, sums, maxs);
    k_mlp<<<N_GRAPHS, 64, 0, stream>>>(sums, maxs, start, W1, b1, W2, b2, out);
}

// Round 13
// 239.174 us; speedup vs baseline: 1.2086x; 1.2086x over previous
//
#include <hip/hip_runtime.h>
#include <hip/hip_fp16.h>

#define N_NODES 50000
#define N_EDGES 1250000
#define HID 64
#define N_LAYERS 3
#define N_GRAPHS 64
#define EPS 1e-5f

// ---- dst-partitioned CSR build ----
#define P_SHIFT 7
#define P_NODES 128                                     // nodes per partition
#define NP ((N_NODES + P_NODES - 1) / P_NODES)          // 391
#define PCAP 4096                                       // slots (mean 3200, +16 sigma)

typedef _Float16 half4f __attribute__((ext_vector_type(4)));
typedef float f32x4 __attribute__((ext_vector_type(4)));

__device__ inline float2 up2(unsigned u) {
    __half2 h;
    *reinterpret_cast<unsigned*>(&h) = u;
    return __half22float2(h);
}
__device__ inline unsigned pk2(float a, float b) {
    __half2 h = __floats2half2_rn(a, b);
    return *reinterpret_cast<unsigned*>(&h);
}

// ------- embed gather: h0[i][:] = fp16(emb[x[i]][:]) ------------------------
__global__ __launch_bounds__(256) void k_embed(const int* __restrict__ x,
                                               const float4* __restrict__ emb4,
                                               uint4* __restrict__ h8) {
    int i = blockIdx.x * 256 + threadIdx.x;           // over N_NODES * 8
    if (i < N_NODES * 8) {
        int row = i >> 3, q = i & 7;
        float4 fa = emb4[x[row] * 16 + q * 2];
        float4 fb = emb4[x[row] * 16 + q * 2 + 1];
        uint4 u;
        u.x = pk2(fa.x, fa.y); u.y = pk2(fa.z, fa.w);
        u.z = pk2(fb.x, fb.y); u.w = pk2(fb.z, fb.w);
        h8[i] = u;
    }
}

// ---- partition edges by dst>>7; per-block contiguous runs (low write-amp) --
__global__ __launch_bounds__(1024) void k_part(const int* __restrict__ src,
                                               const int* __restrict__ dst,
                                               const float* __restrict__ w,
                                               int* __restrict__ pcnt,
                                               int2* __restrict__ part) {
    __shared__ int hist[NP];   // counts, then block base
    __shared__ int cur[NP];
    int t = threadIdx.x;
    for (int k = t; k < NP; k += 1024) { hist[k] = 0; cur[k] = 0; }
    __syncthreads();
    int chunk = (N_EDGES + gridDim.x - 1) / gridDim.x;
    int e0 = blockIdx.x * chunk;
    int e1 = min(e0 + chunk, N_EDGES);
    for (int e = e0 + t; e < e1; e += 1024)
        atomicAdd(&hist[dst[e] >> P_SHIFT], 1);
    __syncthreads();
    for (int k = t; k < NP; k += 1024) {
        int c = hist[k];
        hist[k] = c ? atomicAdd(&pcnt[k], c) : 0;      // reserve block range
    }
    __syncthreads();
    for (int e = e0 + t; e < e1; e += 1024) {
        int d = dst[e];
        int b = d >> P_SHIFT;
        int r = atomicAdd(&cur[b], 1);
        part[(b << 12) + hist[b] + r] =                // PCAP == 4096
            make_int2(((d & (P_NODES - 1)) << 16) | src[e], __float_as_int(w[e]));
    }
}

// ---- per-partition LDS counting sort -> packed 4B CSR ----------------------
// entry = src:16 | half(w):16 ; per-node-contiguous; dst implicit via rowbeg.
// block 0 also computes graph bounds + zeroes pooling scratch
__global__ __launch_bounds__(512) void k_sort(const int2* __restrict__ part,
                                              const int* __restrict__ pcnt,
                                              unsigned* __restrict__ csr16,
                                              int* __restrict__ rowbeg,
                                              int* __restrict__ rowend,
                                              const int* __restrict__ batch,
                                              int* __restrict__ start,
                                              float* __restrict__ sums,
                                              unsigned* __restrict__ maxs) {
    __shared__ int2 sbuf[PCAP];        // 32 KB
    __shared__ int cnt[P_NODES], base[P_NODES], cur[P_NODES];
    int p = blockIdx.x, t = threadIdx.x;
    if (t < P_NODES) cnt[t] = 0;
    __syncthreads();
    int n = pcnt[p];
    if (n > PCAP) n = PCAP;
    const int2* pb = part + (p << 12);
    for (int i = t; i < n; i += 512) atomicAdd(&cnt[pb[i].x >> 16], 1);
    __syncthreads();
    if (t < P_NODES) base[t] = cnt[t];
    __syncthreads();
    for (int off = 1; off < P_NODES; off <<= 1) {
        int v = (t < P_NODES && t >= off) ? base[t - off] : 0;
        __syncthreads();
        if (t < P_NODES) base[t] += v;                 // inclusive scan
        __syncthreads();
    }
    if (t < P_NODES) cur[t] = base[t] - cnt[t];        // exclusive start
    __syncthreads();
    for (int i = t; i < n; i += 512) {
        int2 e = pb[i];
        int pos = atomicAdd(&cur[e.x >> 16], 1);
        sbuf[pos] = e;
    }
    __syncthreads();
    for (int i = t; i < n; i += 512) {                 // packed 4B write
        int2 e = sbuf[i];
        unsigned short wb = __half_as_ushort(__float2half_rn(__int_as_float(e.y)));
        csr16[(p << 12) + i] = (unsigned)(e.x & 0xFFFF) | ((unsigned)wb << 16);
    }
    if (t < P_NODES) {
        int node = p * P_NODES + t;
        if (node < N_NODES) {
            rowbeg[node] = (p << 12) + base[t] - cnt[t];
            rowend[node] = (p << 12) + base[t];
        }
    }
    if (p == 0) {                                      // fused misc work
        if (t <= N_GRAPHS) {
            int lo = 0, hi = N_NODES;
            while (lo < hi) {
                int mid = (lo + hi) >> 1;
                if (batch[mid] < t) lo = mid + 1; else hi = mid;
            }
            start[t] = lo;
        }
        for (int k = t; k < N_GRAPHS * HID; k += 512) {
            sums[k] = 0.f;
            maxs[k] = 0u;
        }
    }
}

// ---- lean gather: agg[n][:] = sum_e w_e * h[src_e][:]  (fp16 in/out) -------
// 512 thr = 8 waves; wave = one node; NO LDS, NO barriers.
// lane = (grp = lane>>3 edge-slot, c8 = lane&7 channel-octet); dwordx4 =
// 8 fp16 channels; 8 rows per instruction; 4 edge-slots (32 edges) in flight.
__global__ __launch_bounds__(512) void k_gather(const uint4* __restrict__ h8,
                                                const int* __restrict__ rowbeg,
                                                const int* __restrict__ rowend,
                                                const unsigned* __restrict__ csr16,
                                                uint4* __restrict__ agg8) {
    int tid = threadIdx.x;
    int wv = tid >> 6, lane = tid & 63;
    int grp = lane >> 3, c8 = lane & 7;
    int row = blockIdx.x * 8 + wv;            // 50000 % 8 == 0 -> exact
    int p0 = __builtin_amdgcn_readfirstlane(rowbeg[row]);
    int p1 = __builtin_amdgcn_readfirstlane(rowend[row]);
    int last = p1 - 1;
    float A0[8], A1[8], A2[8], A3[8];
#pragma unroll
    for (int q = 0; q < 8; ++q) { A0[q] = 0.f; A1[q] = 0.f; A2[q] = 0.f; A3[q] = 0.f; }
    for (int p = p0; p <= last; p += 32) {    // 32 edges per iter, 4 slots
        int i0 = p + grp, i1 = i0 + 8, i2 = i0 + 16, i3 = i0 + 24;
        unsigned e0 = csr16[min(i0, last)];
        unsigned e1 = csr16[min(i1, last)];
        unsigned e2 = csr16[min(i2, last)];
        unsigned e3 = csr16[min(i3, last)];
        float w0 = (i0 <= last) ? __half2float(__ushort_as_half((unsigned short)(e0 >> 16))) : 0.f;
        float w1 = (i1 <= last) ? __half2float(__ushort_as_half((unsigned short)(e1 >> 16))) : 0.f;
        float w2 = (i2 <= last) ? __half2float(__ushort_as_half((unsigned short)(e2 >> 16))) : 0.f;
        float w3 = (i3 <= last) ? __half2float(__ushort_as_half((unsigned short)(e3 >> 16))) : 0.f;
        uint4 v0 = h8[(e0 & 0xFFFF) * 8 + c8];
        uint4 v1 = h8[(e1 & 0xFFFF) * 8 + c8];
        uint4 v2 = h8[(e2 & 0xFFFF) * 8 + c8];
        uint4 v3 = h8[(e3 & 0xFFFF) * 8 + c8];
        float2 f;
        f = up2(v0.x); A0[0] += f.x * w0; A0[1] += f.y * w0;
        f = up2(v0.y); A0[2] += f.x * w0; A0[3] += f.y * w0;
        f = up2(v0.z); A0[4] += f.x * w0; A0[5] += f.y * w0;
        f = up2(v0.w); A0[6] += f.x * w0; A0[7] += f.y * w0;
        f = up2(v1.x); A1[0] += f.x * w1; A1[1] += f.y * w1;
        f = up2(v1.y); A1[2] += f.x * w1; A1[3] += f.y * w1;
        f = up2(v1.z); A1[4] += f.x * w1; A1[5] += f.y * w1;
        f = up2(v1.w); A1[6] += f.x * w1; A1[7] += f.y * w1;
        f = up2(v2.x); A2[0] += f.x * w2; A2[1] += f.y * w2;
        f = up2(v2.y); A2[2] += f.x * w2; A2[3] += f.y * w2;
        f = up2(v2.z); A2[4] += f.x * w2; A2[5] += f.y * w2;
        f = up2(v2.w); A2[6] += f.x * w2; A2[7] += f.y * w2;
        f = up2(v3.x); A3[0] += f.x * w3; A3[1] += f.y * w3;
        f = up2(v3.y); A3[2] += f.x * w3; A3[3] += f.y * w3;
        f = up2(v3.z); A3[4] += f.x * w3; A3[5] += f.y * w3;
        f = up2(v3.w); A3[6] += f.x * w3; A3[7] += f.y * w3;
    }
    float acc[8];
#pragma unroll
    for (int q = 0; q < 8; ++q) {
        float s = (A0[q] + A1[q]) + (A2[q] + A3[q]);
        s += __shfl_xor(s, 8, 64);
        s += __shfl_xor(s, 16, 64);
        s += __shfl_xor(s, 32, 64);
        acc[q] = s;
    }
    if (grp == 0) {                            // lanes 0..7 store 128B/row
        uint4 u;
        u.x = pk2(acc[0], acc[1]); u.y = pk2(acc[2], acc[3]);
        u.z = pk2(acc[4], acc[5]); u.w = pk2(acc[6], acc[7]);
        agg8[row * 8 + c8] = u;
    }
}

// ---- MFMA transform: hout = relu(LN(agg @ W + bias))  ----------------------
// 256 thr = 4 waves; 64 nodes/block; wave w owns rows w*16..w*16+15.
// mfma_f32_16x16x16f16: A row=lane&15,k=(lane>>4)*4+i; B k=(lane>>4)*4+i,
// col=lane&15; C col=lane&15,row=(lane>>4)*4+i (m89-verified family).
#define APITCH 68
__global__ __launch_bounds__(256) void k_xform(const uint4* __restrict__ agg8,
                                               const float* __restrict__ W,
                                               const float* __restrict__ bias,
                                               const float* __restrict__ gam,
                                               const float* __restrict__ bet,
                                               uint4* __restrict__ hout8) {
    __shared__ _Float16 Al[64][APITCH];       // 8704 B
    __shared__ _Float16 Cl[64][APITCH];       // 8704 B
    __shared__ float Wl[HID * HID];           // 16 KB
    __shared__ float prm[3 * HID];            // bias | gamma | beta
    int tid = threadIdx.x;
    int row0 = blockIdx.x * 64;
    // stage A (64 rows x 8 uint4), zero-pad past N_NODES
    for (int idx = tid; idx < 512; idx += 256) {
        int r = idx >> 3, c8 = idx & 7;
        uint4 u = make_uint4(0u, 0u, 0u, 0u);
        if (row0 + r < N_NODES) u = agg8[(row0 + r) * 8 + c8];
        unsigned* dstp = (unsigned*)&Al[r][c8 * 8];
        dstp[0] = u.x; dstp[1] = u.y; dstp[2] = u.z; dstp[3] = u.w;
    }
    for (int idx = tid; idx < HID * HID; idx += 256) Wl[idx] = W[idx];
    if (tid < HID) {
        prm[tid] = bias[tid];
        prm[HID + tid] = gam[tid];
        prm[2 * HID + tid] = bet[tid];
    }
    __syncthreads();
    int wv = tid >> 6, lane = tid & 63;
    int g4 = lane >> 4, l15 = lane & 15;
    f32x4 acc[4] = {f32x4{0,0,0,0}, f32x4{0,0,0,0}, f32x4{0,0,0,0}, f32x4{0,0,0,0}};
#pragma unroll
    for (int kc = 0; kc < 4; ++kc) {
        half4f a = *(const half4f*)&Al[wv * 16 + l15][kc * 16 + g4 * 4];
        int kb = kc * 16 + g4 * 4;
#pragma unroll
        for (int ct = 0; ct < 4; ++ct) {
            int cb = ct * 16 + l15;
            half4f bf;
            bf[0] = (_Float16)Wl[(kb + 0) * HID + cb];
            bf[1] = (_Float16)Wl[(kb + 1) * HID + cb];
            bf[2] = (_Float16)Wl[(kb + 2) * HID + cb];
            bf[3] = (_Float16)Wl[(kb + 3) * HID + cb];
            acc[ct] = __builtin_amdgcn_mfma_f32_16x16x16f16(a, bf, acc[ct], 0, 0, 0);
        }
    }
    // bias, then LayerNorm per row (row = wv*16 + g4*4 + i, 16-lane groups)
#pragma unroll
    for (int ct = 0; ct < 4; ++ct) {
        float bb = prm[ct * 16 + l15];
#pragma unroll
        for (int i = 0; i < 4; ++i) acc[ct][i] += bb;
    }
    float rs[4];
#pragma unroll
    for (int i = 0; i < 4; ++i)
        rs[i] = (acc[0][i] + acc[1][i]) + (acc[2][i] + acc[3][i]);
#pragma unroll
    for (int i = 0; i < 4; ++i) {
        rs[i] += __shfl_xor(rs[i], 1, 64);
        rs[i] += __shfl_xor(rs[i], 2, 64);
        rs[i] += __shfl_xor(rs[i], 4, 64);
        rs[i] += __shfl_xor(rs[i], 8, 64);
    }
    float sq[4];
#pragma unroll
    for (int i = 0; i < 4; ++i) {
        float mu = rs[i] * (1.f / 64.f);
#pragma unroll
        for (int ct = 0; ct < 4; ++ct) acc[ct][i] -= mu;
        sq[i] = (acc[0][i] * acc[0][i] + acc[1][i] * acc[1][i])
              + (acc[2][i] * acc[2][i] + acc[3][i] * acc[3][i]);
    }
#pragma unroll
    for (int i = 0; i < 4; ++i) {
        sq[i] += __shfl_xor(sq[i], 1, 64);
        sq[i] += __shfl_xor(sq[i], 2, 64);
        sq[i] += __shfl_xor(sq[i], 4, 64);
        sq[i] += __shfl_xor(sq[i], 8, 64);
    }
#pragma unroll
    for (int ct = 0; ct < 4; ++ct) {
        int col = ct * 16 + l15;
        float gg = prm[HID + col], bb = prm[2 * HID + col];
#pragma unroll
        for (int i = 0; i < 4; ++i) {
            float scale = rsqrtf(sq[i] * (1.f / 64.f) + EPS);
            float y = fmaxf(acc[ct][i] * scale * gg + bb, 0.f);
            Cl[wv * 16 + g4 * 4 + i][col] = (_Float16)y;
        }
    }
    __syncthreads();
    // copy out (guarded)
    for (int idx = tid; idx < 512; idx += 256) {
        int r = idx >> 3, c8 = idx & 7;
        if (row0 + r < N_NODES) {
            const unsigned* sp = (const unsigned*)&Cl[r][c8 * 8];
            hout8[(row0 + r) * 8 + c8] = make_uint4(sp[0], sp[1], sp[2], sp[3]);
        }
    }
}

// ---------------- pooling: sliced segmented reduction (fp16 input) ----------
#define NSLICE 16
__global__ __launch_bounds__(256) void k_pool2(const unsigned short* __restrict__ h,
                                               const int* __restrict__ start,
                                               float* __restrict__ sums,
                                               unsigned* __restrict__ maxs) {
    int gph = blockIdx.x >> 4;          // / NSLICE
    int sl  = blockIdx.x & (NSLICE - 1);
    int s = start[gph], e1 = start[gph + 1];
    int len = e1 - s;
    int chunk = (len + NSLICE - 1) / NSLICE;
    int r0 = s + sl * chunk;
    int r1 = min(r0 + chunk, e1);
    int j = threadIdx.x & 63, wv = threadIdx.x >> 6;
    float sm = 0.f, mx = 0.f;           // post-ReLU values >= 0
    for (int r = r0 + wv; r < r1; r += 4) {
        float v = __half2float(__ushort_as_half(h[r * HID + j]));
        sm += v;
        mx = fmaxf(mx, v);
    }
    atomicAdd(&sums[gph * HID + j], sm);
    atomicMax(&maxs[gph * HID + j], __float_as_uint(mx));
}

// ---------------- final MLP: relu([mean,max] @ W1 + b1) @ W2 + b2 -----------
__global__ __launch_bounds__(64) void k_mlp(const float* __restrict__ sums,
                                            const unsigned* __restrict__ maxs,
                                            const int* __restrict__ start,
                                            const float* __restrict__ W1,
                                            const float* __restrict__ b1,
                                            const float* __restrict__ W2,
                                            const float* __restrict__ b2,
                                            float* __restrict__ out) {
    int gph = blockIdx.x;
    int j = threadIdx.x;          // 64 threads
    __shared__ float gv[2 * HID];
    int cnt = start[gph + 1] - start[gph];
    float inv = 1.f / fmaxf((float)cnt, 1.f);
    gv[j] = sums[gph * HID + j] * inv;
    float mx = __uint_as_float(maxs[gph * HID + j]);
    gv[HID + j] = (cnt > 0) ? mx : 0.f;
    __syncthreads();
    float acc = b1[j];
#pragma unroll
    for (int k = 0; k < 2 * HID; ++k) acc += gv[k] * W1[k * HID + j];
    acc = fmaxf(acc, 0.f);
    float p = acc * W2[j];
#pragma unroll
    for (int off = 32; off; off >>= 1) p += __shfl_xor(p, off, 64);
    if (j == 0) out[gph] = p + b2[0];
}

extern "C" void kernel_launch(void* const* d_in, const int* in_sizes, int n_in,
                              void* d_out, int out_size, void* d_ws, size_t ws_size,
                              hipStream_t stream) {
    const int*   x     = (const int*)d_in[0];
    const int*   ei    = (const int*)d_in[1];
    const float* ew    = (const float*)d_in[2];
    const int*   batch = (const int*)d_in[3];
    const float* emb   = (const float*)d_in[4];
    const float* convW = (const float*)d_in[5];
    const float* convB = (const float*)d_in[6];
    const float* lnG   = (const float*)d_in[7];
    const float* lnB   = (const float*)d_in[8];
    const float* W1    = (const float*)d_in[9];
    const float* b1    = (const float*)d_in[10];
    const float* W2    = (const float*)d_in[11];
    const float* b2    = (const float*)d_in[12];
    float* out = (float*)d_out;

    // ---- workspace layout (~39 MB) ----
    unsigned short* hA = (unsigned short*)d_ws;           // 6.4 MB (fp16)
    unsigned short* hB = hA + (size_t)N_NODES * HID;      // 6.4 MB (fp16)
    unsigned short* agg = hB + (size_t)N_NODES * HID;     // 6.4 MB (fp16)
    int2*  part   = (int2*)(agg + (size_t)N_NODES * HID); // 12.81 MB
    unsigned* csr16 = (unsigned*)(part + (size_t)NP * PCAP); // 6.25 MB
    int*   pcnt   = (int*)(csr16 + (size_t)NP * PCAP);    // 391
    int*   rowbeg = pcnt + NP;                            // 50000
    int*   rowend = rowbeg + N_NODES;                     // 50000
    float* sums   = (float*)(rowend + N_NODES);           // 4096
    unsigned* maxs = (unsigned*)(sums + N_GRAPHS * HID);  // 4096
    int*   start  = (int*)(maxs + N_GRAPHS * HID);        // 65

    const int* src = ei;
    const int* dst = ei + N_EDGES;

    hipMemsetAsync(pcnt, 0, NP * sizeof(int), stream);
    k_part<<<256, 1024, 0, stream>>>(src, dst, ew, pcnt, part);
    k_sort<<<NP, 512, 0, stream>>>(part, pcnt, csr16, rowbeg, rowend,
                                   batch, start, sums, maxs);
    k_embed<<<(N_NODES * 8 + 255) / 256, 256, 0, stream>>>(
        x, (const float4*)emb, (uint4*)hA);

    unsigned short* bufs[2] = { hA, hB };
    for (int L = 0; L < N_LAYERS; ++L) {
        k_gather<<<N_NODES / 8, 512, 0, stream>>>(
            (const uint4*)bufs[L & 1], rowbeg, rowend, csr16, (uint4*)agg);
        k_xform<<<(N_NODES + 63) / 64, 256, 0, stream>>>(
            (const uint4*)agg, convW + L * HID * HID, convB + L * HID,
            lnG + L * HID, lnB + L * HID, (uint4*)bufs[(L + 1) & 1]);
    }
    const unsigned short* hfin = bufs[N_LAYERS & 1];      // hB after 3 layers

    k_pool2<<<N_GRAPHS * NSLICE, 256, 0, stream>>>(hfin, start, sums, maxs);
    k_mlp<<<N_GRAPHS, 64, 0, stream>>>(sums, maxs, start, W1, b1, W2, b2, out);
}

// Round 14
// 232.932 us; speedup vs baseline: 1.2410x; 1.0268x over previous
//
#include <hip/hip_runtime.h>
#include <hip/hip_fp16.h>

#define N_NODES 50000
#define N_EDGES 1250000
#define HID 64
#define N_LAYERS 3
#define N_GRAPHS 64
#define EPS 1e-5f

// ---- dst-partitioned CSR build ----
#define P_SHIFT 7
#define P_NODES 128                                     // nodes per partition
#define NP ((N_NODES + P_NODES - 1) / P_NODES)          // 391
#define PCAP 4096                                       // slots (mean 3200, +16 sigma)

typedef _Float16 half4f __attribute__((ext_vector_type(4)));
typedef float f32x4 __attribute__((ext_vector_type(4)));

__device__ inline float2 up2(unsigned u) {
    __half2 h;
    *reinterpret_cast<unsigned*>(&h) = u;
    return __half22float2(h);
}
__device__ inline unsigned pk2(float a, float b) {
    __half2 h = __floats2half2_rn(a, b);
    return *reinterpret_cast<unsigned*>(&h);
}

// ------- embed gather: h0[i][:] = fp16(emb[x[i]][:]) ------------------------
__global__ __launch_bounds__(256) void k_embed(const int* __restrict__ x,
                                               const float4* __restrict__ emb4,
                                               uint4* __restrict__ h8) {
    int i = blockIdx.x * 256 + threadIdx.x;           // over N_NODES * 8
    if (i < N_NODES * 8) {
        int row = i >> 3, q = i & 7;
        float4 fa = emb4[x[row] * 16 + q * 2];
        float4 fb = emb4[x[row] * 16 + q * 2 + 1];
        uint4 u;
        u.x = pk2(fa.x, fa.y); u.y = pk2(fa.z, fa.w);
        u.z = pk2(fb.x, fb.y); u.w = pk2(fb.z, fb.w);
        h8[i] = u;
    }
}

// ---- partition edges by dst>>7; per-block contiguous runs (low write-amp) --
__global__ __launch_bounds__(1024) void k_part(const int* __restrict__ src,
                                               const int* __restrict__ dst,
                                               const float* __restrict__ w,
                                               int* __restrict__ pcnt,
                                               int2* __restrict__ part) {
    __shared__ int hist[NP];   // counts, then block base
    __shared__ int cur[NP];
    int t = threadIdx.x;
    for (int k = t; k < NP; k += 1024) { hist[k] = 0; cur[k] = 0; }
    __syncthreads();
    int chunk = (N_EDGES + gridDim.x - 1) / gridDim.x;
    int e0 = blockIdx.x * chunk;
    int e1 = min(e0 + chunk, N_EDGES);
    for (int e = e0 + t; e < e1; e += 1024)
        atomicAdd(&hist[dst[e] >> P_SHIFT], 1);
    __syncthreads();
    for (int k = t; k < NP; k += 1024) {
        int c = hist[k];
        hist[k] = c ? atomicAdd(&pcnt[k], c) : 0;      // reserve block range
    }
    __syncthreads();
    for (int e = e0 + t; e < e1; e += 1024) {
        int d = dst[e];
        int b = d >> P_SHIFT;
        int r = atomicAdd(&cur[b], 1);
        part[(b << 12) + hist[b] + r] =                // PCAP == 4096
            make_int2(((d & (P_NODES - 1)) << 16) | src[e], __float_as_int(w[e]));
    }
}

// ---- per-partition LDS counting sort -> packed 4B CSR ----------------------
// entry = src:16 | half(w):16 ; per-node-contiguous; dst implicit via rowbeg.
// block 0 also computes graph bounds + zeroes pooling scratch
__global__ __launch_bounds__(512) void k_sort(const int2* __restrict__ part,
                                              const int* __restrict__ pcnt,
                                              unsigned* __restrict__ csr16,
                                              int* __restrict__ rowbeg,
                                              int* __restrict__ rowend,
                                              const int* __restrict__ batch,
                                              int* __restrict__ start,
                                              float* __restrict__ sums,
                                              unsigned* __restrict__ maxs) {
    __shared__ int2 sbuf[PCAP];        // 32 KB
    __shared__ int cnt[P_NODES], base[P_NODES], cur[P_NODES];
    int p = blockIdx.x, t = threadIdx.x;
    if (t < P_NODES) cnt[t] = 0;
    __syncthreads();
    int n = pcnt[p];
    if (n > PCAP) n = PCAP;
    const int2* pb = part + (p << 12);
    for (int i = t; i < n; i += 512) atomicAdd(&cnt[pb[i].x >> 16], 1);
    __syncthreads();
    if (t < P_NODES) base[t] = cnt[t];
    __syncthreads();
    for (int off = 1; off < P_NODES; off <<= 1) {
        int v = (t < P_NODES && t >= off) ? base[t - off] : 0;
        __syncthreads();
        if (t < P_NODES) base[t] += v;                 // inclusive scan
        __syncthreads();
    }
    if (t < P_NODES) cur[t] = base[t] - cnt[t];        // exclusive start
    __syncthreads();
    for (int i = t; i < n; i += 512) {
        int2 e = pb[i];
        int pos = atomicAdd(&cur[e.x >> 16], 1);
        sbuf[pos] = e;
    }
    __syncthreads();
    for (int i = t; i < n; i += 512) {                 // packed 4B write
        int2 e = sbuf[i];
        unsigned short wb = __half_as_ushort(__float2half_rn(__int_as_float(e.y)));
        csr16[(p << 12) + i] = (unsigned)(e.x & 0xFFFF) | ((unsigned)wb << 16);
    }
    if (t < P_NODES) {
        int node = p * P_NODES + t;
        if (node < N_NODES) {
            rowbeg[node] = (p << 12) + base[t] - cnt[t];
            rowend[node] = (p << 12) + base[t];
        }
    }
    if (p == 0) {                                      // fused misc work
        if (t <= N_GRAPHS) {
            int lo = 0, hi = N_NODES;
            while (lo < hi) {
                int mid = (lo + hi) >> 1;
                if (batch[mid] < t) lo = mid + 1; else hi = mid;
            }
            start[t] = lo;
        }
        for (int k = t; k < N_GRAPHS * HID; k += 512) {
            sums[k] = 0.f;
            maxs[k] = 0u;
        }
    }
}

// ---- lean gather: agg[n][:] = sum_e w_e * h[src_e][:]  (fp16 in/out) -------
// 512 thr = 8 waves; wave = one node; NO LDS, NO barriers.
__global__ __launch_bounds__(512) void k_gather(const uint4* __restrict__ h8,
                                                const int* __restrict__ rowbeg,
                                                const int* __restrict__ rowend,
                                                const unsigned* __restrict__ csr16,
                                                uint4* __restrict__ agg8) {
    int tid = threadIdx.x;
    int wv = tid >> 6, lane = tid & 63;
    int grp = lane >> 3, c8 = lane & 7;
    int row = blockIdx.x * 8 + wv;            // 50000 % 8 == 0 -> exact
    int p0 = __builtin_amdgcn_readfirstlane(rowbeg[row]);
    int p1 = __builtin_amdgcn_readfirstlane(rowend[row]);
    int last = p1 - 1;
    float A0[8], A1[8], A2[8], A3[8];
#pragma unroll
    for (int q = 0; q < 8; ++q) { A0[q] = 0.f; A1[q] = 0.f; A2[q] = 0.f; A3[q] = 0.f; }
    for (int p = p0; p <= last; p += 32) {    // 32 edges per iter, 4 slots
        int i0 = p + grp, i1 = i0 + 8, i2 = i0 + 16, i3 = i0 + 24;
        unsigned e0 = csr16[min(i0, last)];
        unsigned e1 = csr16[min(i1, last)];
        unsigned e2 = csr16[min(i2, last)];
        unsigned e3 = csr16[min(i3, last)];
        float w0 = (i0 <= last) ? __half2float(__ushort_as_half((unsigned short)(e0 >> 16))) : 0.f;
        float w1 = (i1 <= last) ? __half2float(__ushort_as_half((unsigned short)(e1 >> 16))) : 0.f;
        float w2 = (i2 <= last) ? __half2float(__ushort_as_half((unsigned short)(e2 >> 16))) : 0.f;
        float w3 = (i3 <= last) ? __half2float(__ushort_as_half((unsigned short)(e3 >> 16))) : 0.f;
        uint4 v0 = h8[(e0 & 0xFFFF) * 8 + c8];
        uint4 v1 = h8[(e1 & 0xFFFF) * 8 + c8];
        uint4 v2 = h8[(e2 & 0xFFFF) * 8 + c8];
        uint4 v3 = h8[(e3 & 0xFFFF) * 8 + c8];
        float2 f;
        f = up2(v0.x); A0[0] += f.x * w0; A0[1] += f.y * w0;
        f = up2(v0.y); A0[2] += f.x * w0; A0[3] += f.y * w0;
        f = up2(v0.z); A0[4] += f.x * w0; A0[5] += f.y * w0;
        f = up2(v0.w); A0[6] += f.x * w0; A0[7] += f.y * w0;
        f = up2(v1.x); A1[0] += f.x * w1; A1[1] += f.y * w1;
        f = up2(v1.y); A1[2] += f.x * w1; A1[3] += f.y * w1;
        f = up2(v1.z); A1[4] += f.x * w1; A1[5] += f.y * w1;
        f = up2(v1.w); A1[6] += f.x * w1; A1[7] += f.y * w1;
        f = up2(v2.x); A2[0] += f.x * w2; A2[1] += f.y * w2;
        f = up2(v2.y); A2[2] += f.x * w2; A2[3] += f.y * w2;
        f = up2(v2.z); A2[4] += f.x * w2; A2[5] += f.y * w2;
        f = up2(v2.w); A2[6] += f.x * w2; A2[7] += f.y * w2;
        f = up2(v3.x); A3[0] += f.x * w3; A3[1] += f.y * w3;
        f = up2(v3.y); A3[2] += f.x * w3; A3[3] += f.y * w3;
        f = up2(v3.z); A3[4] += f.x * w3; A3[5] += f.y * w3;
        f = up2(v3.w); A3[6] += f.x * w3; A3[7] += f.y * w3;
    }
    float acc[8];
#pragma unroll
    for (int q = 0; q < 8; ++q) {
        float s = (A0[q] + A1[q]) + (A2[q] + A3[q]);
        s += __shfl_xor(s, 8, 64);
        s += __shfl_xor(s, 16, 64);
        s += __shfl_xor(s, 32, 64);
        acc[q] = s;
    }
    if (grp == 0) {                            // lanes 0..7 store 128B/row
        uint4 u;
        u.x = pk2(acc[0], acc[1]); u.y = pk2(acc[2], acc[3]);
        u.z = pk2(acc[4], acc[5]); u.w = pk2(acc[6], acc[7]);
        agg8[row * 8 + c8] = u;
    }
}

// ---- MFMA transform: y = relu(LN(agg @ W + bias)); POOL=1 fuses pooling ----
// 256 thr = 4 waves; 64 nodes/block; wave w owns rows w*16..w*16+15.
// mfma_f32_16x16x16f16 C layout: col=lane&15, row=(lane>>4)*4+i (m89 family).
#define APITCH 68
template<int POOL>
__global__ __launch_bounds__(256) void k_xform(const uint4* __restrict__ agg8,
                                               const float* __restrict__ W,
                                               const float* __restrict__ bias,
                                               const float* __restrict__ gam,
                                               const float* __restrict__ bet,
                                               uint4* __restrict__ hout8,
                                               const int* __restrict__ batch,
                                               float* __restrict__ sums,
                                               unsigned* __restrict__ maxs) {
    __shared__ _Float16 Al[64][APITCH];       // 8704 B
    __shared__ _Float16 Cl[64][APITCH];       // 8704 B (unused when POOL)
    __shared__ float Wl[HID * HID];           // 16 KB
    __shared__ float prm[3 * HID];            // bias | gamma | beta
    __shared__ int gbs[64];
    int tid = threadIdx.x;
    int row0 = blockIdx.x * 64;
    // stage A (64 rows x 8 uint4), zero-pad past N_NODES
    for (int idx = tid; idx < 512; idx += 256) {
        int r = idx >> 3, c8 = idx & 7;
        uint4 u = make_uint4(0u, 0u, 0u, 0u);
        if (row0 + r < N_NODES) u = agg8[(row0 + r) * 8 + c8];
        unsigned* dstp = (unsigned*)&Al[r][c8 * 8];
        dstp[0] = u.x; dstp[1] = u.y; dstp[2] = u.z; dstp[3] = u.w;
    }
    for (int idx = tid; idx < HID * HID; idx += 256) Wl[idx] = W[idx];
    if (tid < HID) {
        prm[tid] = bias[tid];
        prm[HID + tid] = gam[tid];
        prm[2 * HID + tid] = bet[tid];
    }
    if (POOL && tid < 64)
        gbs[tid] = (row0 + tid < N_NODES) ? batch[row0 + tid] : -1;
    __syncthreads();
    int wv = tid >> 6, lane = tid & 63;
    int g4 = lane >> 4, l15 = lane & 15;
    f32x4 acc[4] = {f32x4{0,0,0,0}, f32x4{0,0,0,0}, f32x4{0,0,0,0}, f32x4{0,0,0,0}};
#pragma unroll
    for (int kc = 0; kc < 4; ++kc) {
        half4f a = *(const half4f*)&Al[wv * 16 + l15][kc * 16 + g4 * 4];
        int kb = kc * 16 + g4 * 4;
#pragma unroll
        for (int ct = 0; ct < 4; ++ct) {
            int cb = ct * 16 + l15;
            half4f bf;
            bf[0] = (_Float16)Wl[(kb + 0) * HID + cb];
            bf[1] = (_Float16)Wl[(kb + 1) * HID + cb];
            bf[2] = (_Float16)Wl[(kb + 2) * HID + cb];
            bf[3] = (_Float16)Wl[(kb + 3) * HID + cb];
            acc[ct] = __builtin_amdgcn_mfma_f32_16x16x16f16(a, bf, acc[ct], 0, 0, 0);
        }
    }
    // bias, then LayerNorm per row (row = wv*16 + g4*4 + i, 16-lane groups)
#pragma unroll
    for (int ct = 0; ct < 4; ++ct) {
        float bb = prm[ct * 16 + l15];
#pragma unroll
        for (int i = 0; i < 4; ++i) acc[ct][i] += bb;
    }
    float rs[4];
#pragma unroll
    for (int i = 0; i < 4; ++i)
        rs[i] = (acc[0][i] + acc[1][i]) + (acc[2][i] + acc[3][i]);
#pragma unroll
    for (int i = 0; i < 4; ++i) {
        rs[i] += __shfl_xor(rs[i], 1, 64);
        rs[i] += __shfl_xor(rs[i], 2, 64);
        rs[i] += __shfl_xor(rs[i], 4, 64);
        rs[i] += __shfl_xor(rs[i], 8, 64);
    }
    float sq[4];
#pragma unroll
    for (int i = 0; i < 4; ++i) {
        float mu = rs[i] * (1.f / 64.f);
#pragma unroll
        for (int ct = 0; ct < 4; ++ct) acc[ct][i] -= mu;
        sq[i] = (acc[0][i] * acc[0][i] + acc[1][i] * acc[1][i])
              + (acc[2][i] * acc[2][i] + acc[3][i] * acc[3][i]);
    }
#pragma unroll
    for (int i = 0; i < 4; ++i) {
        sq[i] += __shfl_xor(sq[i], 1, 64);
        sq[i] += __shfl_xor(sq[i], 2, 64);
        sq[i] += __shfl_xor(sq[i], 4, 64);
        sq[i] += __shfl_xor(sq[i], 8, 64);
    }
#pragma unroll
    for (int ct = 0; ct < 4; ++ct) {
        int col = ct * 16 + l15;
        float gg = prm[HID + col], bb = prm[2 * HID + col];
#pragma unroll
        for (int i = 0; i < 4; ++i) {
            float scale = rsqrtf(sq[i] * (1.f / 64.f) + EPS);
            acc[ct][i] = fmaxf(acc[ct][i] * scale * gg + bb, 0.f);   // y
        }
    }
    if (POOL) {
        // per-graph masked column reduction; block spans few graphs
        int lastv = min(63, N_NODES - 1 - row0);
        int gmin = gbs[0], gmax = gbs[lastv];
        for (int g = gmin; g <= gmax; ++g) {
            float ps[4], pm[4];
#pragma unroll
            for (int ct = 0; ct < 4; ++ct) { ps[ct] = 0.f; pm[ct] = 0.f; }
#pragma unroll
            for (int i = 0; i < 4; ++i) {
                int r = wv * 16 + g4 * 4 + i;
                bool ok = (gbs[r] == g);
#pragma unroll
                for (int ct = 0; ct < 4; ++ct) {
                    float yv = ok ? acc[ct][i] : 0.f;
                    ps[ct] += yv;
                    pm[ct] = fmaxf(pm[ct], yv);
                }
            }
#pragma unroll
            for (int ct = 0; ct < 4; ++ct) {
                ps[ct] += __shfl_xor(ps[ct], 16, 64);
                ps[ct] += __shfl_xor(ps[ct], 32, 64);
                pm[ct] = fmaxf(pm[ct], __shfl_xor(pm[ct], 16, 64));
                pm[ct] = fmaxf(pm[ct], __shfl_xor(pm[ct], 32, 64));
            }
            if (g4 == 0) {
#pragma unroll
                for (int ct = 0; ct < 4; ++ct) {
                    atomicAdd(&sums[g * HID + ct * 16 + l15], ps[ct]);
                    atomicMax(&maxs[g * HID + ct * 16 + l15],
                              __float_as_uint(pm[ct]));
                }
            }
        }
    } else {
#pragma unroll
        for (int ct = 0; ct < 4; ++ct) {
            int col = ct * 16 + l15;
#pragma unroll
            for (int i = 0; i < 4; ++i)
                Cl[wv * 16 + g4 * 4 + i][col] = (_Float16)acc[ct][i];
        }
        __syncthreads();
        for (int idx = tid; idx < 512; idx += 256) {
            int r = idx >> 3, c8 = idx & 7;
            if (row0 + r < N_NODES) {
                const unsigned* sp = (const unsigned*)&Cl[r][c8 * 8];
                hout8[(row0 + r) * 8 + c8] = make_uint4(sp[0], sp[1], sp[2], sp[3]);
            }
        }
    }
}

// ---------------- final MLP: relu([mean,max] @ W1 + b1) @ W2 + b2 -----------
__global__ __launch_bounds__(64) void k_mlp(const float* __restrict__ sums,
                                            const unsigned* __restrict__ maxs,
                                            const int* __restrict__ start,
                                            const float* __restrict__ W1,
                                            const float* __restrict__ b1,
                                            const float* __restrict__ W2,
                                            const float* __restrict__ b2,
                                            float* __restrict__ out) {
    int gph = blockIdx.x;
    int j = threadIdx.x;          // 64 threads
    __shared__ float gv[2 * HID];
    int cnt = start[gph + 1] - start[gph];
    float inv = 1.f / fmaxf((float)cnt, 1.f);
    gv[j] = sums[gph * HID + j] * inv;
    float mx = __uint_as_float(maxs[gph * HID + j]);
    gv[HID + j] = (cnt > 0) ? mx : 0.f;
    __syncthreads();
    float acc = b1[j];
#pragma unroll
    for (int k = 0; k < 2 * HID; ++k) acc += gv[k] * W1[k * HID + j];
    acc = fmaxf(acc, 0.f);
    float p = acc * W2[j];
#pragma unroll
    for (int off = 32; off; off >>= 1) p += __shfl_xor(p, off, 64);
    if (j == 0) out[gph] = p + b2[0];
}

extern "C" void kernel_launch(void* const* d_in, const int* in_sizes, int n_in,
                              void* d_out, int out_size, void* d_ws, size_t ws_size,
                              hipStream_t stream) {
    const int*   x     = (const int*)d_in[0];
    const int*   ei    = (const int*)d_in[1];
    const float* ew    = (const float*)d_in[2];
    const int*   batch = (const int*)d_in[3];
    const float* emb   = (const float*)d_in[4];
    const float* convW = (const float*)d_in[5];
    const float* convB = (const float*)d_in[6];
    const float* lnG   = (const float*)d_in[7];
    const float* lnB   = (const float*)d_in[8];
    const float* W1    = (const float*)d_in[9];
    const float* b1    = (const float*)d_in[10];
    const float* W2    = (const float*)d_in[11];
    const float* b2    = (const float*)d_in[12];
    float* out = (float*)d_out;

    // ---- workspace layout (~39 MB) ----
    unsigned short* hA = (unsigned short*)d_ws;           // 6.4 MB (fp16)
    unsigned short* hB = hA + (size_t)N_NODES * HID;      // 6.4 MB (fp16)
    unsigned short* agg = hB + (size_t)N_NODES * HID;     // 6.4 MB (fp16)
    int2*  part   = (int2*)(agg + (size_t)N_NODES * HID); // 12.81 MB
    unsigned* csr16 = (unsigned*)(part + (size_t)NP * PCAP); // 6.25 MB
    int*   pcnt   = (int*)(csr16 + (size_t)NP * PCAP);    // 391
    int*   rowbeg = pcnt + NP;                            // 50000
    int*   rowend = rowbeg + N_NODES;                     // 50000
    float* sums   = (float*)(rowend + N_NODES);           // 4096
    unsigned* maxs = (unsigned*)(sums + N_GRAPHS * HID);  // 4096
    int*   start  = (int*)(maxs + N_GRAPHS * HID);        // 65

    const int* src = ei;
    const int* dst = ei + N_EDGES;

    hipMemsetAsync(pcnt, 0, NP * sizeof(int), stream);
    k_part<<<256, 1024, 0, stream>>>(src, dst, ew, pcnt, part);
    k_sort<<<NP, 512, 0, stream>>>(part, pcnt, csr16, rowbeg, rowend,
                                   batch, start, sums, maxs);
    k_embed<<<(N_NODES * 8 + 255) / 256, 256, 0, stream>>>(
        x, (const float4*)emb, (uint4*)hA);

    unsigned short* bufs[2] = { hA, hB };
    const int XG = (N_NODES + 63) / 64;
    for (int L = 0; L < N_LAYERS; ++L) {
        k_gather<<<N_NODES / 8, 512, 0, stream>>>(
            (const uint4*)bufs[L & 1], rowbeg, rowend, csr16, (uint4*)agg);
        if (L < N_LAYERS - 1) {
            k_xform<0><<<XG, 256, 0, stream>>>(
                (const uint4*)agg, convW + L * HID * HID, convB + L * HID,
                lnG + L * HID, lnB + L * HID, (uint4*)bufs[(L + 1) & 1],
                batch, sums, maxs);
        } else {
            k_xform<1><<<XG, 256, 0, stream>>>(
                (const uint4*)agg, convW + L * HID * HID, convB + L * HID,
                lnG + L * HID, lnB + L * HID, (uint4*)bufs[(L + 1) & 1],
                batch, sums, maxs);
        }
    }

    k_mlp<<<N_GRAPHS, 64, 0, stream>>>(sums, maxs, start, W1, b1, W2, b2, out);
}